// Round 8
// baseline (706.853 us; speedup 1.0000x reference)
//
#include <hip/hip_runtime.h>
#include <math.h>

#define NPTS 6144
#define CH   128

typedef __attribute__((ext_vector_type(8))) short short8;
typedef __attribute__((ext_vector_type(4))) float f32x4;
typedef __attribute__((ext_vector_type(2))) float f32x2;
typedef __attribute__((ext_vector_type(4))) int   i32x4;

__device__ inline ushort f2bf(float f) {
  union { float f; unsigned u; } v; v.f = f;
  unsigned u = v.u;
  u += 0x7fff + ((u >> 16) & 1);   // round-to-nearest-even
  return (ushort)(u >> 16);
}

__device__ inline f32x2 splat2(float x) { return (f32x2){x, x}; }

__device__ inline float fsqrt(float x) {
  float r; asm("v_sqrt_f32 %0, %1" : "=v"(r) : "v"(x)); return r;
}
__device__ inline float fexp2(float x) {
  float r; asm("v_exp_f32 %0, %1" : "=v"(r) : "v"(x)); return r;
}

// ---------------------------------------------------------------------------
// Kernel 1: embedding  feat = [corr_feat, centered(kp)] @ W_in + b_in
// ---------------------------------------------------------------------------
__global__ __launch_bounds__(128) void k_embed(
    const float* __restrict__ refp, const float* __restrict__ srcp,
    const float* __restrict__ cf, const float* __restrict__ Win,
    const float* __restrict__ bin, float* __restrict__ out) {
  const int row = blockIdx.x, j = threadIdx.x;
  __shared__ float inb[12];
  __shared__ float mkp;
  if (j < 6)       inb[j] = cf[row * 6 + j];
  else if (j < 9)  inb[j] = refp[row * 3 + (j - 6)];
  else if (j < 12) inb[j] = srcp[row * 3 + (j - 9)];
  __syncthreads();
  if (j == 0) {
    float s = inb[6] + inb[7] + inb[8] + inb[9] + inb[10] + inb[11];
    mkp = s * (1.0f / 6.0f);
  }
  __syncthreads();
  float acc = bin[j];
  #pragma unroll
  for (int kk = 0; kk < 12; kk++) {
    float x = inb[kk] - (kk >= 6 ? mkp : 0.0f);
    acc = fmaf(x, Win[kk * CH + j], acc);
  }
  out[row * CH + j] = acc;
}

// ---------------------------------------------------------------------------
// Kernel 2: fused UnaryBlock (linear+LN+leaky) + QKV projection, 8 rows/block.
// Writes T (residual), bf16 Q (pre-scaled log2e/sqrt(C)), K row-major, and
// V transposed AND chunk-permuted: key k -> pos 32a+8b+4h+lo within its
// 64-tile (a=(k>>5)&1, b=(k>>2)&3, h=(k>>4)&1, lo=k&3) so attn PV A-frags
// are contiguous 16B chunks.
// ---------------------------------------------------------------------------
__global__ __launch_bounds__(128) void k_mlp_qkv(
    const float* __restrict__ X, const float* __restrict__ W,
    const float* __restrict__ b, const float* __restrict__ g,
    const float* __restrict__ beta,
    const float* __restrict__ Wq, const float* __restrict__ bq,
    const float* __restrict__ Wk, const float* __restrict__ bk,
    const float* __restrict__ Wv, const float* __restrict__ bv,
    float* __restrict__ T, ushort* __restrict__ Q, ushort* __restrict__ K,
    ushort* __restrict__ Vt) {
  const int j = threadIdx.x;
  const int r0 = blockIdx.x * 8;
  __shared__ float xs[8][CH];
  __shared__ float hs[8][CH];
  __shared__ float red[2][8];
  #pragma unroll
  for (int r = 0; r < 8; r++) xs[r][j] = X[(r0 + r) * CH + j];
  __syncthreads();

  // ---- phase 1: h = leaky(LN(x @ W + b)) ----
  float acc[8];
  const float bj = b[j];
  #pragma unroll
  for (int r = 0; r < 8; r++) acc[r] = bj;
  for (int kk = 0; kk < CH; kk++) {
    float wv_ = W[kk * CH + j];
    #pragma unroll
    for (int r = 0; r < 8; r++) acc[r] = fmaf(xs[r][kk], wv_, acc[r]);
  }
  const int wv2 = j >> 6, ln = j & 63;
  float sum[8];
  #pragma unroll
  for (int r = 0; r < 8; r++) sum[r] = acc[r];
  #pragma unroll
  for (int o = 32; o; o >>= 1) {
    #pragma unroll
    for (int r = 0; r < 8; r++) sum[r] += __shfl_xor(sum[r], o);
  }
  if (ln == 0) {
    #pragma unroll
    for (int r = 0; r < 8; r++) red[wv2][r] = sum[r];
  }
  __syncthreads();
  float dv[8];
  #pragma unroll
  for (int r = 0; r < 8; r++) {
    float mean = (red[0][r] + red[1][r]) * (1.0f / 128.0f);
    dv[r] = acc[r] - mean;
    sum[r] = dv[r] * dv[r];
  }
  #pragma unroll
  for (int o = 32; o; o >>= 1) {
    #pragma unroll
    for (int r = 0; r < 8; r++) sum[r] += __shfl_xor(sum[r], o);
  }
  __syncthreads();
  if (ln == 0) {
    #pragma unroll
    for (int r = 0; r < 8; r++) red[wv2][r] = sum[r];
  }
  __syncthreads();
  const float gj = g[j], betaj = beta[j];
  #pragma unroll
  for (int r = 0; r < 8; r++) {
    float var = (red[0][r] + red[1][r]) * (1.0f / 128.0f);
    float y = dv[r] * rsqrtf(var + 1e-5f) * gj + betaj;
    y = (y > 0.0f) ? y : 0.1f * y;
    T[(r0 + r) * CH + j] = y;
    hs[r][j] = y;
  }
  __syncthreads();

  // ---- phase 2: Q, K, V from h ----
  float aq[8], ak[8], av[8];
  const float bqj = bq[j], bkj = bk[j], bvj = bv[j];
  #pragma unroll
  for (int r = 0; r < 8; r++) { aq[r] = bqj; ak[r] = bkj; av[r] = bvj; }
  for (int kk = 0; kk < CH; kk++) {
    float wq = Wq[kk * CH + j], wk = Wk[kk * CH + j], wv_ = Wv[kk * CH + j];
    #pragma unroll
    for (int r = 0; r < 8; r++) {
      float x = hs[r][kk];
      aq[r] = fmaf(x, wq, aq[r]);
      ak[r] = fmaf(x, wk, ak[r]);
      av[r] = fmaf(x, wv_, av[r]);
    }
  }
  const float scale = 0.12751879524143007f;  // 1/sqrt(128) * log2(e)
  #pragma unroll
  for (int r = 0; r < 8; r++) {
    Q[(r0 + r) * CH + j] = f2bf(aq[r] * scale);
    K[(r0 + r) * CH + j] = f2bf(ak[r]);
  }
  #pragma unroll
  for (int h = 0; h < 2; h++) {
    const int k0 = r0 + 4 * h;
    const int w0 = k0 & 63;
    const int pos = (k0 & ~63) + 32 * ((w0 >> 5) & 1) + 8 * ((w0 >> 2) & 3) +
                    4 * ((w0 >> 4) & 1);
    ushort4 vp;
    vp.x = f2bf(av[4 * h]);     vp.y = f2bf(av[4 * h + 1]);
    vp.z = f2bf(av[4 * h + 2]); vp.w = f2bf(av[4 * h + 3]);
    *(ushort4*)(Vt + (size_t)j * NPTS + pos) = vp;
  }
}

// ---------------------------------------------------------------------------
// Kernel 3: MFMA flash attention, KV-split. 512 threads = 8 waves, 128 q-rows.
// Register-staged (L2-friendly) double-buffered K, single-buffered V,
// XOR-swizzled unpadded LDS (write & read), 2 barriers/tile.
// 49.5 KB LDS -> 3 blocks/CU; NS=16 -> 768 blocks = one full residency round.
// ---------------------------------------------------------------------------
__global__ __launch_bounds__(512, 6) void k_attn_mfma(
    const ushort* __restrict__ Q, const ushort* __restrict__ K,
    const ushort* __restrict__ Vt,
    const float* __restrict__ refp, const float* __restrict__ srcp,
    float* __restrict__ Opart, float* __restrict__ ML, int ntiles) {
  const int tid = threadIdx.x;
  const int w = tid >> 6, ln = tid & 63;
  const int l15 = ln & 15, g = ln >> 4;
  const int row0 = blockIdx.x * 128;
  const int seg = blockIdx.y;
  const int t0 = seg * ntiles;

  __shared__ ushort Ks[2][64][128];   // chunk c of row r stored at c^(r&7)
  __shared__ ushort Vs[128][64];      // chunk c of ch row stored at c^(ch&7)
  __shared__ float cs2[6][64];

  // staging geometry: linear global reads, swizzled LDS writes
  const int krow = tid >> 4;                         // 0..31
  const int kc   = tid & 15;
  const int kofs = krow * 256 + (((kc ^ (krow & 7)) << 4));
  const int vch  = tid >> 3;                         // 0..63
  const int vc   = tid & 7;
  const int vofs = vch * 128 + (((vc ^ (vch & 7)) << 4));

  short8 kreg0, kreg1, vreg0, vreg1;
  float cr[6];

  auto issue = [&](int t) {
    const ushort* kp = K + (size_t)(t * 64 + krow) * CH + kc * 8;
    kreg0 = *(const short8*)kp;
    kreg1 = *(const short8*)(kp + (size_t)32 * CH);
    const ushort* vp = Vt + (size_t)vch * NPTS + t * 64 + vc * 8;
    vreg0 = *(const short8*)vp;
    vreg1 = *(const short8*)(vp + (size_t)64 * NPTS);
    if (tid < 64) {
      int gj = t * 64 + tid;
      cr[0] = refp[gj * 3]; cr[1] = refp[gj * 3 + 1]; cr[2] = refp[gj * 3 + 2];
      cr[3] = srcp[gj * 3]; cr[4] = srcp[gj * 3 + 1]; cr[5] = srcp[gj * 3 + 2];
    }
  };

  // Q B-fragment
  short8 qf[4];
  {
    const ushort* qp = Q + (size_t)(row0 + 16 * w + l15) * CH + 8 * g;
    #pragma unroll
    for (int ks = 0; ks < 4; ks++) qf[ks] = *(const short8*)(qp + 32 * ks);
  }
  const int qrow = row0 + 16 * w + l15;
  const float rq0 = refp[qrow * 3], rq1 = refp[qrow * 3 + 1], rq2 = refp[qrow * 3 + 2];
  const float sq0 = srcp[qrow * 3], sq1 = srcp[qrow * 3 + 1], sq2 = srcp[qrow * 3 + 2];

  f32x4 oacc[8];
  #pragma unroll
  for (int n = 0; n < 8; n++) oacc[n] = (f32x4){0.f, 0.f, 0.f, 0.f};
  float m = -1e30f, l = 0.0f;
  const float invs2 = 1.0f / (0.3f * 0.3f);

  // ---- prologue: stage tile t0 ----
  issue(t0);
  *(short8*)((char*)&Ks[0][0][0] + kofs) = kreg0;
  *(short8*)((char*)&Ks[0][0][0] + kofs + 32 * 256) = kreg1;
  *(short8*)((char*)&Vs[0][0] + vofs) = vreg0;
  *(short8*)((char*)&Vs[0][0] + vofs + 64 * 128) = vreg1;
  if (tid < 64) {
    #pragma unroll
    for (int d = 0; d < 6; d++) cs2[d][tid] = cr[d];
  }
  __syncthreads();

  int cb = 0;
  for (int tt = 0; tt < ntiles; tt++) {
    if (tt + 1 < ntiles) issue(t0 + tt + 1);

    // ---- S^T = K @ Q^T : lane holds S[q=l15][key=16nb+4g+r] ----
    f32x4 acc[4];
    #pragma unroll
    for (int nb = 0; nb < 4; nb++) acc[nb] = (f32x4){0.f, 0.f, 0.f, 0.f};
    __builtin_amdgcn_s_setprio(1);
    #pragma unroll
    for (int ks = 0; ks < 4; ks++) {
      #pragma unroll
      for (int nb = 0; nb < 4; nb++) {
        const char* src = (const char*)&Ks[cb][0][0] + (16 * nb + l15) * 256 +
                          (((4 * ks + g) ^ (l15 & 7)) << 4);
        short8 af = *(const short8*)src;
        acc[nb] = __builtin_amdgcn_mfma_f32_16x16x32_bf16(af, qf[ks], acc[nb], 0, 0, 0);
      }
    }
    __builtin_amdgcn_s_setprio(0);

    // ---- geo * S (log2 domain) ----
    float plog[4][4];
    #pragma unroll
    for (int nb = 0; nb < 4; nb++) {
      const int kb = 16 * nb + 4 * g;
      #pragma unroll
      for (int pp = 0; pp < 2; pp++) {
        const int k2 = kb + 2 * pp;
        f32x2 cx = *(const f32x2*)&cs2[0][k2];
        f32x2 cy = *(const f32x2*)&cs2[1][k2];
        f32x2 cz = *(const f32x2*)&cs2[2][k2];
        f32x2 dx = splat2(rq0) - cx, dy = splat2(rq1) - cy, dz = splat2(rq2) - cz;
        f32x2 d2r = dx * dx + dy * dy + dz * dz;
        cx = *(const f32x2*)&cs2[3][k2];
        cy = *(const f32x2*)&cs2[4][k2];
        cz = *(const f32x2*)&cs2[5][k2];
        dx = splat2(sq0) - cx; dy = splat2(sq1) - cy; dz = splat2(sq2) - cz;
        f32x2 d2s = dx * dx + dy * dy + dz * dz;
        f32x2 prod = d2r * d2s;
        f32x2 sum2 = d2r + d2s;
        float s0 = fsqrt(prod[0]), s1 = fsqrt(prod[1]);
        float dd20 = fmaf(-2.0f, s0, sum2[0]);   // (dr - ds)^2
        float dd21 = fmaf(-2.0f, s1, sum2[1]);
        float gg0 = fmaxf(fmaf(dd20, -invs2, 1.0f), 0.0f);
        float gg1 = fmaxf(fmaf(dd21, -invs2, 1.0f), 0.0f);
        plog[nb][2 * pp]     = gg0 * acc[nb][2 * pp];
        plog[nb][2 * pp + 1] = gg1 * acc[nb][2 * pp + 1];
      }
    }

    // ---- online softmax (defer-rescale) ----
    float tm = fmaxf(fmaxf(plog[0][0], plog[0][1]), fmaxf(plog[0][2], plog[0][3]));
    #pragma unroll
    for (int nb = 1; nb < 4; nb++) {
      float t2 = fmaxf(fmaxf(plog[nb][0], plog[nb][1]),
                       fmaxf(plog[nb][2], plog[nb][3]));
      tm = fmaxf(tm, t2);
    }
    tm = fmaxf(tm, __shfl_xor(tm, 16));
    tm = fmaxf(tm, __shfl_xor(tm, 32));
    if (__any(tm > m + 11.0f)) {
      float nm = fmaxf(m, tm);
      float rsc = fexp2(m - nm);
      l *= rsc;
      #pragma unroll
      for (int n = 0; n < 8; n++) oacc[n] *= rsc;
      m = nm;
    }
    float psum = 0.0f;
    #pragma unroll
    for (int nb = 0; nb < 4; nb++)
      #pragma unroll
      for (int r = 0; r < 4; r++) {
        float p = fexp2(plog[nb][r] - m);
        plog[nb][r] = p;
        psum += p;
      }
    psum += __shfl_xor(psum, 16);
    psum += __shfl_xor(psum, 32);
    l += psum;

    unsigned pk[4][2];
    #pragma unroll
    for (int nb = 0; nb < 4; nb++) {
      asm("v_cvt_pk_bf16_f32 %0, %1, %2"
          : "=v"(pk[nb][0]) : "v"(plog[nb][0]), "v"(plog[nb][1]));
      asm("v_cvt_pk_bf16_f32 %0, %1, %2"
          : "=v"(pk[nb][1]) : "v"(plog[nb][2]), "v"(plog[nb][3]));
    }

    __syncthreads();   // ===== barrier B: Ks[cb]/cs2 reads done =====

    if (tt + 1 < ntiles) {   // commit K(t+1) -> Ks[cb^1], coords -> cs2
      *(short8*)((char*)&Ks[cb ^ 1][0][0] + kofs) = kreg0;
      *(short8*)((char*)&Ks[cb ^ 1][0][0] + kofs + 32 * 256) = kreg1;
      if (tid < 64) {
        #pragma unroll
        for (int d = 0; d < 6; d++) cs2[d][tid] = cr[d];
      }
    }

    // ---- O^T += V'(pre-permuted) @ P^T ----
    union U16 { i32x4 i; short8 s; };
    __builtin_amdgcn_s_setprio(1);
    #pragma unroll
    for (int ks2 = 0; ks2 < 2; ks2++) {
      U16 bfr;
      bfr.i[0] = (int)pk[2 * ks2][0];
      bfr.i[1] = (int)pk[2 * ks2][1];
      bfr.i[2] = (int)pk[2 * ks2 + 1][0];
      bfr.i[3] = (int)pk[2 * ks2 + 1][1];
      #pragma unroll
      for (int nb2 = 0; nb2 < 8; nb2++) {
        const char* vsrc = (const char*)&Vs[0][0] + (16 * nb2 + l15) * 128 +
                           (((4 * ks2 + g) ^ (l15 & 7)) << 4);
        short8 vf = *(const short8*)vsrc;
        oacc[nb2] = __builtin_amdgcn_mfma_f32_16x16x32_bf16(vf, bfr.s, oacc[nb2], 0, 0, 0);
      }
    }
    __builtin_amdgcn_s_setprio(0);

    __syncthreads();   // ===== barrier C: Vs reads done =====

    if (tt + 1 < ntiles) {   // commit V(t+1) -> Vs
      *(short8*)((char*)&Vs[0][0] + vofs) = vreg0;
      *(short8*)((char*)&Vs[0][0] + vofs + 64 * 128) = vreg1;
    }
    cb ^= 1;
  }

  {
    float* op = Opart + ((size_t)seg * NPTS + qrow) * CH;
    #pragma unroll
    for (int nb2 = 0; nb2 < 8; nb2++)
      *(f32x4*)(op + 16 * nb2 + 4 * g) = oacc[nb2];
    if (g == 0) {
      ML[((size_t)seg * NPTS + qrow) * 2]     = m;
      ML[((size_t)seg * NPTS + qrow) * 2 + 1] = l;
    }
  }
}

// ---------------------------------------------------------------------------
// Kernel 4: fused combine(NS partials) + out-proj + residual + LN, 8 rows/blk.
// ---------------------------------------------------------------------------
__global__ __launch_bounds__(128) void k_out(
    const float* __restrict__ Opart, const float* __restrict__ ML, int NS,
    const float* __restrict__ W, const float* __restrict__ b,
    const float* __restrict__ g, const float* __restrict__ beta,
    const float* __restrict__ res, float* __restrict__ out) {
  const int j = threadIdx.x;
  const int r0 = blockIdx.x * 8;
  __shared__ float xs[8][CH];
  __shared__ float red[2][8];

  // ---- combine phase ----
  #pragma unroll
  for (int r = 0; r < 8; r++) {
    const int row = r0 + r;
    float M = -1e30f;
    for (int s = 0; s < NS; s++)
      M = fmaxf(M, ML[((size_t)s * NPTS + row) * 2]);
    float L = 0.0f, a = 0.0f;
    for (int s = 0; s < NS; s++) {
      float ms = ML[((size_t)s * NPTS + row) * 2];
      float ls = ML[((size_t)s * NPTS + row) * 2 + 1];
      float wsc = fexp2(ms - M);
      L += wsc * ls;
      a = fmaf(wsc, Opart[((size_t)s * NPTS + row) * CH + j], a);
    }
    xs[r][j] = a / L;
  }
  __syncthreads();

  // ---- GEMM + residual + LN ----
  float acc[8];
  const float bj = b[j];
  #pragma unroll
  for (int r = 0; r < 8; r++) acc[r] = bj;
  for (int kk = 0; kk < CH; kk++) {
    float wv_ = W[kk * CH + j];
    #pragma unroll
    for (int r = 0; r < 8; r++) acc[r] = fmaf(xs[r][kk], wv_, acc[r]);
  }
  #pragma unroll
  for (int r = 0; r < 8; r++) acc[r] += res[(r0 + r) * CH + j];

  const int wv2 = j >> 6, ln = j & 63;
  float sum[8];
  #pragma unroll
  for (int r = 0; r < 8; r++) sum[r] = acc[r];
  #pragma unroll
  for (int o = 32; o; o >>= 1) {
    #pragma unroll
    for (int r = 0; r < 8; r++) sum[r] += __shfl_xor(sum[r], o);
  }
  if (ln == 0) {
    #pragma unroll
    for (int r = 0; r < 8; r++) red[wv2][r] = sum[r];
  }
  __syncthreads();
  float dv[8];
  #pragma unroll
  for (int r = 0; r < 8; r++) {
    float mean = (red[0][r] + red[1][r]) * (1.0f / 128.0f);
    dv[r] = acc[r] - mean;
    sum[r] = dv[r] * dv[r];
  }
  #pragma unroll
  for (int o = 32; o; o >>= 1) {
    #pragma unroll
    for (int r = 0; r < 8; r++) sum[r] += __shfl_xor(sum[r], o);
  }
  __syncthreads();
  if (ln == 0) {
    #pragma unroll
    for (int r = 0; r < 8; r++) red[wv2][r] = sum[r];
  }
  __syncthreads();
  const float gj = g[j], betaj = beta[j];
  #pragma unroll
  for (int r = 0; r < 8; r++) {
    float var = (red[0][r] + red[1][r]) * (1.0f / 128.0f);
    out[(r0 + r) * CH + j] = dv[r] * rsqrtf(var + 1e-5f) * gj + betaj;
  }
}

// ---------------------------------------------------------------------------
// Kernel 5: final row normalize + classifier MLP + sigmoid
// ---------------------------------------------------------------------------
__global__ __launch_bounds__(128) void k_final(
    const float* __restrict__ F,
    const float* __restrict__ c1W, const float* __restrict__ c1b,
    const float* __restrict__ c2W, const float* __restrict__ c2b,
    const float* __restrict__ c3W, const float* __restrict__ c3b,
    float* __restrict__ out) {
  const int row = blockIdx.x, j = threadIdx.x;
  __shared__ float xs[CH];
  __shared__ float h1[32];
  __shared__ float h2[32];
  __shared__ float red[2];
  float x = F[row * CH + j];
  float ss = x * x;
  #pragma unroll
  for (int o = 32; o; o >>= 1) ss += __shfl_xor(ss, o);
  if ((j & 63) == 0) red[j >> 6] = ss;
  __syncthreads();
  float norm = sqrtf(red[0] + red[1]);
  float xn = x / fmaxf(norm, 1e-12f);
  xs[j] = xn;
  out[row * CH + j] = xn;
  __syncthreads();
  if (j < 32) {
    float a = c1b[j];
    for (int kk = 0; kk < CH; kk++) a = fmaf(xs[kk], c1W[kk * 32 + j], a);
    h1[j] = fmaxf(a, 0.0f);
  }
  __syncthreads();
  if (j < 32) {
    float a = c2b[j];
    #pragma unroll
    for (int kk = 0; kk < 32; kk++) a = fmaf(h1[kk], c2W[kk * 32 + j], a);
    h2[j] = fmaxf(a, 0.0f);
  }
  __syncthreads();
  if (j == 0) {
    float a = c3b[0];
    #pragma unroll
    for (int kk = 0; kk < 32; kk++) a = fmaf(h2[kk], c3W[kk], a);
    out[NPTS * CH + row] = 1.0f / (1.0f + __expf(-a));
  }
}

// ---------------------------------------------------------------------------
extern "C" void kernel_launch(void* const* d_in, const int* in_sizes, int n_in,
                              void* d_out, int out_size, void* d_ws, size_t ws_size,
                              hipStream_t stream) {
  const float* refp = (const float*)d_in[0];
  const float* srcp = (const float*)d_in[1];
  const float* cf   = (const float*)d_in[2];
  const float* Win  = (const float*)d_in[3];
  const float* bin  = (const float*)d_in[4];
  const float* mlpW = (const float*)d_in[5];
  const float* mlpb = (const float*)d_in[6];
  const float* mlpg = (const float*)d_in[7];
  const float* mlpbeta = (const float*)d_in[8];
  const float* Wq = (const float*)d_in[9];
  const float* bq = (const float*)d_in[10];
  const float* Wk = (const float*)d_in[11];
  const float* bk = (const float*)d_in[12];
  const float* Wv = (const float*)d_in[13];
  const float* bv = (const float*)d_in[14];
  const float* Wo = (const float*)d_in[15];
  const float* bo = (const float*)d_in[16];
  const float* lng = (const float*)d_in[17];
  const float* lnb = (const float*)d_in[18];
  const float* c1W = (const float*)d_in[19];
  const float* c1b = (const float*)d_in[20];
  const float* c2W = (const float*)d_in[21];
  const float* c2b = (const float*)d_in[22];
  const float* c3W = (const float*)d_in[23];
  const float* c3b = (const float*)d_in[24];
  float* out = (float*)d_out;

  const size_t NC = (size_t)NPTS * CH;
  float* F = (float*)d_ws;
  float* T = F + NC;
  ushort* Qb  = (ushort*)(T + NC);
  ushort* Kb  = Qb + NC;
  ushort* Vtb = Kb + NC;
  float* Opart = (float*)(Vtb + NC);

  // pick largest KV-split that fits the workspace
  const size_t base_bytes = 2 * NC * 4 + 3 * NC * 2;
  int NS = 1;
  for (int cand = 16; cand >= 2; cand >>= 1) {
    size_t need = base_bytes + (size_t)cand * (NC * 4 + NPTS * 8);
    if (need <= ws_size) { NS = cand; break; }
  }
  float* ML = Opart + (size_t)NS * NC;
  const int ntiles = NPTS / 64 / NS;

  k_embed<<<NPTS, 128, 0, stream>>>(refp, srcp, cf, Win, bin, F);
  for (int i = 0; i < 3; i++) {
    const int o2 = i * CH * CH, o1 = i * CH;
    k_mlp_qkv<<<NPTS / 8, 128, 0, stream>>>(
        F, mlpW + o2, mlpb + o1, mlpg + o1, mlpbeta + o1,
        Wq + o2, bq + o1, Wk + o2, bk + o1, Wv + o2, bv + o1,
        T, Qb, Kb, Vtb);
    dim3 agrid(NPTS / 128, NS);
    k_attn_mfma<<<agrid, 512, 0, stream>>>(Qb, Kb, Vtb, refp, srcp, Opart, ML, ntiles);
    k_out<<<NPTS / 8, 128, 0, stream>>>(Opart, ML, NS, Wo + o2, bo + o1,
                                        lng + o1, lnb + o1, T, F);
  }
  k_final<<<NPTS, 128, 0, stream>>>(F, c1W, c1b, c2W, c2b, c3W, c3b, out);
}

// Round 9
// 461.295 us; speedup vs baseline: 1.5323x; 1.5323x over previous
//
#include <hip/hip_runtime.h>
#include <math.h>

#define NPTS 6144
#define CH   128

typedef __attribute__((ext_vector_type(8))) short short8;
typedef __attribute__((ext_vector_type(4))) float f32x4;
typedef __attribute__((ext_vector_type(2))) float f32x2;
typedef __attribute__((ext_vector_type(4))) int   i32x4;

__device__ inline ushort f2bf(float f) {
  union { float f; unsigned u; } v; v.f = f;
  unsigned u = v.u;
  u += 0x7fff + ((u >> 16) & 1);   // round-to-nearest-even
  return (ushort)(u >> 16);
}

__device__ inline f32x2 splat2(float x) { return (f32x2){x, x}; }

__device__ inline float fsqrt(float x) {
  float r; asm("v_sqrt_f32 %0, %1" : "=v"(r) : "v"(x)); return r;
}
__device__ inline float fexp2(float x) {
  float r; asm("v_exp_f32 %0, %1" : "=v"(r) : "v"(x)); return r;
}

// ---------------------------------------------------------------------------
// Kernel 1: embedding  feat = [corr_feat, centered(kp)] @ W_in + b_in
// ---------------------------------------------------------------------------
__global__ __launch_bounds__(128) void k_embed(
    const float* __restrict__ refp, const float* __restrict__ srcp,
    const float* __restrict__ cf, const float* __restrict__ Win,
    const float* __restrict__ bin, float* __restrict__ out) {
  const int row = blockIdx.x, j = threadIdx.x;
  __shared__ float inb[12];
  __shared__ float mkp;
  if (j < 6)       inb[j] = cf[row * 6 + j];
  else if (j < 9)  inb[j] = refp[row * 3 + (j - 6)];
  else if (j < 12) inb[j] = srcp[row * 3 + (j - 9)];
  __syncthreads();
  if (j == 0) {
    float s = inb[6] + inb[7] + inb[8] + inb[9] + inb[10] + inb[11];
    mkp = s * (1.0f / 6.0f);
  }
  __syncthreads();
  float acc = bin[j];
  #pragma unroll
  for (int kk = 0; kk < 12; kk++) {
    float x = inb[kk] - (kk >= 6 ? mkp : 0.0f);
    acc = fmaf(x, Win[kk * CH + j], acc);
  }
  out[row * CH + j] = acc;
}

// ---------------------------------------------------------------------------
// Kernel 2: fused UnaryBlock (linear+LN+leaky) + QKV projection, 8 rows/block.
// Writes T (residual), bf16 Q (pre-scaled log2e/sqrt(C)), K row-major, and
// V transposed AND chunk-permuted: key k -> pos 32a+8b+4h+lo within its
// 64-tile (a=(k>>5)&1, b=(k>>2)&3, h=(k>>4)&1, lo=k&3) so attn PV A-frags
// are contiguous 16B chunks.
// ---------------------------------------------------------------------------
__global__ __launch_bounds__(128) void k_mlp_qkv(
    const float* __restrict__ X, const float* __restrict__ W,
    const float* __restrict__ b, const float* __restrict__ g,
    const float* __restrict__ beta,
    const float* __restrict__ Wq, const float* __restrict__ bq,
    const float* __restrict__ Wk, const float* __restrict__ bk,
    const float* __restrict__ Wv, const float* __restrict__ bv,
    float* __restrict__ T, ushort* __restrict__ Q, ushort* __restrict__ K,
    ushort* __restrict__ Vt) {
  const int j = threadIdx.x;
  const int r0 = blockIdx.x * 8;
  __shared__ float xs[8][CH];
  __shared__ float hs[8][CH];
  __shared__ float red[2][8];
  #pragma unroll
  for (int r = 0; r < 8; r++) xs[r][j] = X[(r0 + r) * CH + j];
  __syncthreads();

  // ---- phase 1: h = leaky(LN(x @ W + b)) ----
  float acc[8];
  const float bj = b[j];
  #pragma unroll
  for (int r = 0; r < 8; r++) acc[r] = bj;
  for (int kk = 0; kk < CH; kk++) {
    float wv_ = W[kk * CH + j];
    #pragma unroll
    for (int r = 0; r < 8; r++) acc[r] = fmaf(xs[r][kk], wv_, acc[r]);
  }
  const int wv2 = j >> 6, ln = j & 63;
  float sum[8];
  #pragma unroll
  for (int r = 0; r < 8; r++) sum[r] = acc[r];
  #pragma unroll
  for (int o = 32; o; o >>= 1) {
    #pragma unroll
    for (int r = 0; r < 8; r++) sum[r] += __shfl_xor(sum[r], o);
  }
  if (ln == 0) {
    #pragma unroll
    for (int r = 0; r < 8; r++) red[wv2][r] = sum[r];
  }
  __syncthreads();
  float dv[8];
  #pragma unroll
  for (int r = 0; r < 8; r++) {
    float mean = (red[0][r] + red[1][r]) * (1.0f / 128.0f);
    dv[r] = acc[r] - mean;
    sum[r] = dv[r] * dv[r];
  }
  #pragma unroll
  for (int o = 32; o; o >>= 1) {
    #pragma unroll
    for (int r = 0; r < 8; r++) sum[r] += __shfl_xor(sum[r], o);
  }
  __syncthreads();
  if (ln == 0) {
    #pragma unroll
    for (int r = 0; r < 8; r++) red[wv2][r] = sum[r];
  }
  __syncthreads();
  const float gj = g[j], betaj = beta[j];
  #pragma unroll
  for (int r = 0; r < 8; r++) {
    float var = (red[0][r] + red[1][r]) * (1.0f / 128.0f);
    float y = dv[r] * rsqrtf(var + 1e-5f) * gj + betaj;
    y = (y > 0.0f) ? y : 0.1f * y;
    T[(r0 + r) * CH + j] = y;
    hs[r][j] = y;
  }
  __syncthreads();

  // ---- phase 2: Q, K, V from h ----
  float aq[8], ak[8], av[8];
  const float bqj = bq[j], bkj = bk[j], bvj = bv[j];
  #pragma unroll
  for (int r = 0; r < 8; r++) { aq[r] = bqj; ak[r] = bkj; av[r] = bvj; }
  for (int kk = 0; kk < CH; kk++) {
    float wq = Wq[kk * CH + j], wk = Wk[kk * CH + j], wv_ = Wv[kk * CH + j];
    #pragma unroll
    for (int r = 0; r < 8; r++) {
      float x = hs[r][kk];
      aq[r] = fmaf(x, wq, aq[r]);
      ak[r] = fmaf(x, wk, ak[r]);
      av[r] = fmaf(x, wv_, av[r]);
    }
  }
  const float scale = 0.12751879524143007f;  // 1/sqrt(128) * log2(e)
  #pragma unroll
  for (int r = 0; r < 8; r++) {
    Q[(r0 + r) * CH + j] = f2bf(aq[r] * scale);
    K[(r0 + r) * CH + j] = f2bf(ak[r]);
  }
  #pragma unroll
  for (int h = 0; h < 2; h++) {
    const int k0 = r0 + 4 * h;
    const int w0 = k0 & 63;
    const int pos = (k0 & ~63) + 32 * ((w0 >> 5) & 1) + 8 * ((w0 >> 2) & 3) +
                    4 * ((w0 >> 4) & 1);
    ushort4 vp;
    vp.x = f2bf(av[4 * h]);     vp.y = f2bf(av[4 * h + 1]);
    vp.z = f2bf(av[4 * h + 2]); vp.w = f2bf(av[4 * h + 3]);
    *(ushort4*)(Vt + (size_t)j * NPTS + pos) = vp;
  }
}

// ---------------------------------------------------------------------------
// Kernel 3: MFMA flash attention, KV-split. 512 threads = 8 waves, 128 q-rows.
// Register-staged (L2-friendly) double-buffered K, single-buffered V,
// XOR-swizzled unpadded LDS (write & read), 2 barriers/tile. 49.5 KB LDS.
// __launch_bounds__(512,4): VGPR cap 128 -> NO SPILL (r8's (512,6) forced
// VGPR=40 < 48 live accumulator regs -> 280MB scratch fetch, 2.2x slower).
// ---------------------------------------------------------------------------
__global__ __launch_bounds__(512, 4) void k_attn_mfma(
    const ushort* __restrict__ Q, const ushort* __restrict__ K,
    const ushort* __restrict__ Vt,
    const float* __restrict__ refp, const float* __restrict__ srcp,
    float* __restrict__ Opart, float* __restrict__ ML, int ntiles) {
  const int tid = threadIdx.x;
  const int w = tid >> 6, ln = tid & 63;
  const int l15 = ln & 15, g = ln >> 4;
  const int row0 = blockIdx.x * 128;
  const int seg = blockIdx.y;
  const int t0 = seg * ntiles;

  __shared__ ushort Ks[2][64][128];   // chunk c of row r stored at c^(r&7)
  __shared__ ushort Vs[128][64];      // chunk c of ch row stored at c^(ch&7)
  __shared__ float cs2[6][64];

  // staging geometry: linear global reads, swizzled LDS writes
  const int krow = tid >> 4;                         // 0..31
  const int kc   = tid & 15;
  const int kofs = krow * 256 + (((kc ^ (krow & 7)) << 4));
  const int vch  = tid >> 3;                         // 0..63
  const int vc   = tid & 7;
  const int vofs = vch * 128 + (((vc ^ (vch & 7)) << 4));

  short8 kreg0, kreg1, vreg0, vreg1;
  float cr[6];

  auto issue = [&](int t) {
    const ushort* kp = K + (size_t)(t * 64 + krow) * CH + kc * 8;
    kreg0 = *(const short8*)kp;
    kreg1 = *(const short8*)(kp + (size_t)32 * CH);
    const ushort* vp = Vt + (size_t)vch * NPTS + t * 64 + vc * 8;
    vreg0 = *(const short8*)vp;
    vreg1 = *(const short8*)(vp + (size_t)64 * NPTS);
    if (tid < 64) {
      int gj = t * 64 + tid;
      cr[0] = refp[gj * 3]; cr[1] = refp[gj * 3 + 1]; cr[2] = refp[gj * 3 + 2];
      cr[3] = srcp[gj * 3]; cr[4] = srcp[gj * 3 + 1]; cr[5] = srcp[gj * 3 + 2];
    }
  };

  // Q B-fragment
  short8 qf[4];
  {
    const ushort* qp = Q + (size_t)(row0 + 16 * w + l15) * CH + 8 * g;
    #pragma unroll
    for (int ks = 0; ks < 4; ks++) qf[ks] = *(const short8*)(qp + 32 * ks);
  }
  const int qrow = row0 + 16 * w + l15;
  const float rq0 = refp[qrow * 3], rq1 = refp[qrow * 3 + 1], rq2 = refp[qrow * 3 + 2];
  const float sq0 = srcp[qrow * 3], sq1 = srcp[qrow * 3 + 1], sq2 = srcp[qrow * 3 + 2];

  f32x4 oacc[8];
  #pragma unroll
  for (int n = 0; n < 8; n++) oacc[n] = (f32x4){0.f, 0.f, 0.f, 0.f};
  float m = -1e30f, l = 0.0f;
  const float invs2 = 1.0f / (0.3f * 0.3f);

  // ---- prologue: stage tile t0 ----
  issue(t0);
  *(short8*)((char*)&Ks[0][0][0] + kofs) = kreg0;
  *(short8*)((char*)&Ks[0][0][0] + kofs + 32 * 256) = kreg1;
  *(short8*)((char*)&Vs[0][0] + vofs) = vreg0;
  *(short8*)((char*)&Vs[0][0] + vofs + 64 * 128) = vreg1;
  if (tid < 64) {
    #pragma unroll
    for (int d = 0; d < 6; d++) cs2[d][tid] = cr[d];
  }
  __syncthreads();

  int cb = 0;
  for (int tt = 0; tt < ntiles; tt++) {
    if (tt + 1 < ntiles) issue(t0 + tt + 1);

    // ---- S^T = K @ Q^T : lane holds S[q=l15][key=16nb+4g+r] ----
    f32x4 acc[4];
    #pragma unroll
    for (int nb = 0; nb < 4; nb++) acc[nb] = (f32x4){0.f, 0.f, 0.f, 0.f};
    __builtin_amdgcn_s_setprio(1);
    #pragma unroll
    for (int ks = 0; ks < 4; ks++) {
      #pragma unroll
      for (int nb = 0; nb < 4; nb++) {
        const char* src = (const char*)&Ks[cb][0][0] + (16 * nb + l15) * 256 +
                          (((4 * ks + g) ^ (l15 & 7)) << 4);
        short8 af = *(const short8*)src;
        acc[nb] = __builtin_amdgcn_mfma_f32_16x16x32_bf16(af, qf[ks], acc[nb], 0, 0, 0);
      }
    }
    __builtin_amdgcn_s_setprio(0);

    // ---- geo * S (log2 domain) ----
    float plog[4][4];
    #pragma unroll
    for (int nb = 0; nb < 4; nb++) {
      const int kb = 16 * nb + 4 * g;
      #pragma unroll
      for (int pp = 0; pp < 2; pp++) {
        const int k2 = kb + 2 * pp;
        f32x2 cx = *(const f32x2*)&cs2[0][k2];
        f32x2 cy = *(const f32x2*)&cs2[1][k2];
        f32x2 cz = *(const f32x2*)&cs2[2][k2];
        f32x2 dx = splat2(rq0) - cx, dy = splat2(rq1) - cy, dz = splat2(rq2) - cz;
        f32x2 d2r = dx * dx + dy * dy + dz * dz;
        cx = *(const f32x2*)&cs2[3][k2];
        cy = *(const f32x2*)&cs2[4][k2];
        cz = *(const f32x2*)&cs2[5][k2];
        dx = splat2(sq0) - cx; dy = splat2(sq1) - cy; dz = splat2(sq2) - cz;
        f32x2 d2s = dx * dx + dy * dy + dz * dz;
        f32x2 prod = d2r * d2s;
        f32x2 sum2 = d2r + d2s;
        float s0 = fsqrt(prod[0]), s1 = fsqrt(prod[1]);
        float dd20 = fmaf(-2.0f, s0, sum2[0]);   // (dr - ds)^2
        float dd21 = fmaf(-2.0f, s1, sum2[1]);
        float gg0 = fmaxf(fmaf(dd20, -invs2, 1.0f), 0.0f);
        float gg1 = fmaxf(fmaf(dd21, -invs2, 1.0f), 0.0f);
        plog[nb][2 * pp]     = gg0 * acc[nb][2 * pp];
        plog[nb][2 * pp + 1] = gg1 * acc[nb][2 * pp + 1];
      }
    }

    // ---- online softmax (defer-rescale) ----
    float tm = fmaxf(fmaxf(plog[0][0], plog[0][1]), fmaxf(plog[0][2], plog[0][3]));
    #pragma unroll
    for (int nb = 1; nb < 4; nb++) {
      float t2 = fmaxf(fmaxf(plog[nb][0], plog[nb][1]),
                       fmaxf(plog[nb][2], plog[nb][3]));
      tm = fmaxf(tm, t2);
    }
    tm = fmaxf(tm, __shfl_xor(tm, 16));
    tm = fmaxf(tm, __shfl_xor(tm, 32));
    if (__any(tm > m + 11.0f)) {
      float nm = fmaxf(m, tm);
      float rsc = fexp2(m - nm);
      l *= rsc;
      #pragma unroll
      for (int n = 0; n < 8; n++) oacc[n] *= rsc;
      m = nm;
    }
    float psum = 0.0f;
    #pragma unroll
    for (int nb = 0; nb < 4; nb++)
      #pragma unroll
      for (int r = 0; r < 4; r++) {
        float p = fexp2(plog[nb][r] - m);
        plog[nb][r] = p;
        psum += p;
      }
    psum += __shfl_xor(psum, 16);
    psum += __shfl_xor(psum, 32);
    l += psum;

    unsigned pk[4][2];
    #pragma unroll
    for (int nb = 0; nb < 4; nb++) {
      asm("v_cvt_pk_bf16_f32 %0, %1, %2"
          : "=v"(pk[nb][0]) : "v"(plog[nb][0]), "v"(plog[nb][1]));
      asm("v_cvt_pk_bf16_f32 %0, %1, %2"
          : "=v"(pk[nb][1]) : "v"(plog[nb][2]), "v"(plog[nb][3]));
    }

    __syncthreads();   // ===== barrier B: Ks[cb]/cs2 reads done =====

    if (tt + 1 < ntiles) {   // commit K(t+1) -> Ks[cb^1], coords -> cs2
      *(short8*)((char*)&Ks[cb ^ 1][0][0] + kofs) = kreg0;
      *(short8*)((char*)&Ks[cb ^ 1][0][0] + kofs + 32 * 256) = kreg1;
      if (tid < 64) {
        #pragma unroll
        for (int d = 0; d < 6; d++) cs2[d][tid] = cr[d];
      }
    }

    // ---- O^T += V'(pre-permuted) @ P^T ----
    union U16 { i32x4 i; short8 s; };
    __builtin_amdgcn_s_setprio(1);
    #pragma unroll
    for (int ks2 = 0; ks2 < 2; ks2++) {
      U16 bfr;
      bfr.i[0] = (int)pk[2 * ks2][0];
      bfr.i[1] = (int)pk[2 * ks2][1];
      bfr.i[2] = (int)pk[2 * ks2 + 1][0];
      bfr.i[3] = (int)pk[2 * ks2 + 1][1];
      #pragma unroll
      for (int nb2 = 0; nb2 < 8; nb2++) {
        const char* vsrc = (const char*)&Vs[0][0] + (16 * nb2 + l15) * 128 +
                           (((4 * ks2 + g) ^ (l15 & 7)) << 4);
        short8 vf = *(const short8*)vsrc;
        oacc[nb2] = __builtin_amdgcn_mfma_f32_16x16x32_bf16(vf, bfr.s, oacc[nb2], 0, 0, 0);
      }
    }
    __builtin_amdgcn_s_setprio(0);

    __syncthreads();   // ===== barrier C: Vs reads done =====

    if (tt + 1 < ntiles) {   // commit V(t+1) -> Vs
      *(short8*)((char*)&Vs[0][0] + vofs) = vreg0;
      *(short8*)((char*)&Vs[0][0] + vofs + 64 * 128) = vreg1;
    }
    cb ^= 1;
  }

  {
    float* op = Opart + ((size_t)seg * NPTS + qrow) * CH;
    #pragma unroll
    for (int nb2 = 0; nb2 < 8; nb2++)
      *(f32x4*)(op + 16 * nb2 + 4 * g) = oacc[nb2];
    if (g == 0) {
      ML[((size_t)seg * NPTS + qrow) * 2]     = m;
      ML[((size_t)seg * NPTS + qrow) * 2 + 1] = l;
    }
  }
}

// ---------------------------------------------------------------------------
// Kernel 4: fused combine(NS partials) + out-proj + residual + LN, 8 rows/blk.
// ---------------------------------------------------------------------------
__global__ __launch_bounds__(128) void k_out(
    const float* __restrict__ Opart, const float* __restrict__ ML, int NS,
    const float* __restrict__ W, const float* __restrict__ b,
    const float* __restrict__ g, const float* __restrict__ beta,
    const float* __restrict__ res, float* __restrict__ out) {
  const int j = threadIdx.x;
  const int r0 = blockIdx.x * 8;
  __shared__ float xs[8][CH];
  __shared__ float red[2][8];

  // ---- combine phase ----
  #pragma unroll
  for (int r = 0; r < 8; r++) {
    const int row = r0 + r;
    float M = -1e30f;
    for (int s = 0; s < NS; s++)
      M = fmaxf(M, ML[((size_t)s * NPTS + row) * 2]);
    float L = 0.0f, a = 0.0f;
    for (int s = 0; s < NS; s++) {
      float ms = ML[((size_t)s * NPTS + row) * 2];
      float ls = ML[((size_t)s * NPTS + row) * 2 + 1];
      float wsc = fexp2(ms - M);
      L += wsc * ls;
      a = fmaf(wsc, Opart[((size_t)s * NPTS + row) * CH + j], a);
    }
    xs[r][j] = a / L;
  }
  __syncthreads();

  // ---- GEMM + residual + LN ----
  float acc[8];
  const float bj = b[j];
  #pragma unroll
  for (int r = 0; r < 8; r++) acc[r] = bj;
  for (int kk = 0; kk < CH; kk++) {
    float wv_ = W[kk * CH + j];
    #pragma unroll
    for (int r = 0; r < 8; r++) acc[r] = fmaf(xs[r][kk], wv_, acc[r]);
  }
  #pragma unroll
  for (int r = 0; r < 8; r++) acc[r] += res[(r0 + r) * CH + j];

  const int wv2 = j >> 6, ln = j & 63;
  float sum[8];
  #pragma unroll
  for (int r = 0; r < 8; r++) sum[r] = acc[r];
  #pragma unroll
  for (int o = 32; o; o >>= 1) {
    #pragma unroll
    for (int r = 0; r < 8; r++) sum[r] += __shfl_xor(sum[r], o);
  }
  if (ln == 0) {
    #pragma unroll
    for (int r = 0; r < 8; r++) red[wv2][r] = sum[r];
  }
  __syncthreads();
  float dv[8];
  #pragma unroll
  for (int r = 0; r < 8; r++) {
    float mean = (red[0][r] + red[1][r]) * (1.0f / 128.0f);
    dv[r] = acc[r] - mean;
    sum[r] = dv[r] * dv[r];
  }
  #pragma unroll
  for (int o = 32; o; o >>= 1) {
    #pragma unroll
    for (int r = 0; r < 8; r++) sum[r] += __shfl_xor(sum[r], o);
  }
  __syncthreads();
  if (ln == 0) {
    #pragma unroll
    for (int r = 0; r < 8; r++) red[wv2][r] = sum[r];
  }
  __syncthreads();
  const float gj = g[j], betaj = beta[j];
  #pragma unroll
  for (int r = 0; r < 8; r++) {
    float var = (red[0][r] + red[1][r]) * (1.0f / 128.0f);
    out[(r0 + r) * CH + j] = dv[r] * rsqrtf(var + 1e-5f) * gj + betaj;
  }
}

// ---------------------------------------------------------------------------
// Kernel 5: final row normalize + classifier MLP + sigmoid
// ---------------------------------------------------------------------------
__global__ __launch_bounds__(128) void k_final(
    const float* __restrict__ F,
    const float* __restrict__ c1W, const float* __restrict__ c1b,
    const float* __restrict__ c2W, const float* __restrict__ c2b,
    const float* __restrict__ c3W, const float* __restrict__ c3b,
    float* __restrict__ out) {
  const int row = blockIdx.x, j = threadIdx.x;
  __shared__ float xs[CH];
  __shared__ float h1[32];
  __shared__ float h2[32];
  __shared__ float red[2];
  float x = F[row * CH + j];
  float ss = x * x;
  #pragma unroll
  for (int o = 32; o; o >>= 1) ss += __shfl_xor(ss, o);
  if ((j & 63) == 0) red[j >> 6] = ss;
  __syncthreads();
  float norm = sqrtf(red[0] + red[1]);
  float xn = x / fmaxf(norm, 1e-12f);
  xs[j] = xn;
  out[row * CH + j] = xn;
  __syncthreads();
  if (j < 32) {
    float a = c1b[j];
    for (int kk = 0; kk < CH; kk++) a = fmaf(xs[kk], c1W[kk * 32 + j], a);
    h1[j] = fmaxf(a, 0.0f);
  }
  __syncthreads();
  if (j < 32) {
    float a = c2b[j];
    #pragma unroll
    for (int kk = 0; kk < 32; kk++) a = fmaf(h1[kk], c2W[kk * 32 + j], a);
    h2[j] = fmaxf(a, 0.0f);
  }
  __syncthreads();
  if (j == 0) {
    float a = c3b[0];
    #pragma unroll
    for (int kk = 0; kk < 32; kk++) a = fmaf(h2[kk], c3W[kk], a);
    out[NPTS * CH + row] = 1.0f / (1.0f + __expf(-a));
  }
}

// ---------------------------------------------------------------------------
extern "C" void kernel_launch(void* const* d_in, const int* in_sizes, int n_in,
                              void* d_out, int out_size, void* d_ws, size_t ws_size,
                              hipStream_t stream) {
  const float* refp = (const float*)d_in[0];
  const float* srcp = (const float*)d_in[1];
  const float* cf   = (const float*)d_in[2];
  const float* Win  = (const float*)d_in[3];
  const float* bin  = (const float*)d_in[4];
  const float* mlpW = (const float*)d_in[5];
  const float* mlpb = (const float*)d_in[6];
  const float* mlpg = (const float*)d_in[7];
  const float* mlpbeta = (const float*)d_in[8];
  const float* Wq = (const float*)d_in[9];
  const float* bq = (const float*)d_in[10];
  const float* Wk = (const float*)d_in[11];
  const float* bk = (const float*)d_in[12];
  const float* Wv = (const float*)d_in[13];
  const float* bv = (const float*)d_in[14];
  const float* Wo = (const float*)d_in[15];
  const float* bo = (const float*)d_in[16];
  const float* lng = (const float*)d_in[17];
  const float* lnb = (const float*)d_in[18];
  const float* c1W = (const float*)d_in[19];
  const float* c1b = (const float*)d_in[20];
  const float* c2W = (const float*)d_in[21];
  const float* c2b = (const float*)d_in[22];
  const float* c3W = (const float*)d_in[23];
  const float* c3b = (const float*)d_in[24];
  float* out = (float*)d_out;

  const size_t NC = (size_t)NPTS * CH;
  float* F = (float*)d_ws;
  float* T = F + NC;
  ushort* Qb  = (ushort*)(T + NC);
  ushort* Kb  = Qb + NC;
  ushort* Vtb = Kb + NC;
  float* Opart = (float*)(Vtb + NC);

  // pick largest KV-split that fits the workspace
  const size_t base_bytes = 2 * NC * 4 + 3 * NC * 2;
  int NS = 1;
  for (int cand = 16; cand >= 2; cand >>= 1) {
    size_t need = base_bytes + (size_t)cand * (NC * 4 + NPTS * 8);
    if (need <= ws_size) { NS = cand; break; }
  }
  float* ML = Opart + (size_t)NS * NC;
  const int ntiles = NPTS / 64 / NS;

  k_embed<<<NPTS, 128, 0, stream>>>(refp, srcp, cf, Win, bin, F);
  for (int i = 0; i < 3; i++) {
    const int o2 = i * CH * CH, o1 = i * CH;
    k_mlp_qkv<<<NPTS / 8, 128, 0, stream>>>(
        F, mlpW + o2, mlpb + o1, mlpg + o1, mlpbeta + o1,
        Wq + o2, bq + o1, Wk + o2, bk + o1, Wv + o2, bv + o1,
        T, Qb, Kb, Vtb);
    dim3 agrid(NPTS / 128, NS);
    k_attn_mfma<<<agrid, 512, 0, stream>>>(Qb, Kb, Vtb, refp, srcp, Opart, ML, ntiles);
    k_out<<<NPTS / 8, 128, 0, stream>>>(Opart, ML, NS, Wo + o2, bo + o1,
                                        lng + o1, lnb + o1, T, F);
  }
  k_final<<<NPTS, 128, 0, stream>>>(F, c1W, c1b, c2W, c2b, c3W, c3b, out);
}

// Round 10
// 380.918 us; speedup vs baseline: 1.8557x; 1.2110x over previous
//
#include <hip/hip_runtime.h>
#include <math.h>

#define NPTS 6144
#define CH   128

typedef __attribute__((ext_vector_type(8))) short short8;
typedef __attribute__((ext_vector_type(4))) float f32x4;
typedef __attribute__((ext_vector_type(2))) float f32x2;
typedef __attribute__((ext_vector_type(4))) int   i32x4;

__device__ inline ushort f2bf(float f) {
  union { float f; unsigned u; } v; v.f = f;
  unsigned u = v.u;
  u += 0x7fff + ((u >> 16) & 1);   // round-to-nearest-even
  return (ushort)(u >> 16);
}

__device__ inline f32x2 splat2(float x) { return (f32x2){x, x}; }

__device__ inline float fsqrt(float x) {
  float r; asm("v_sqrt_f32 %0, %1" : "=v"(r) : "v"(x)); return r;
}
__device__ inline float fexp2(float x) {
  float r; asm("v_exp_f32 %0, %1" : "=v"(r) : "v"(x)); return r;
}
__device__ inline unsigned cvtpk(float a, float b) {
  unsigned r;
  asm("v_cvt_pk_bf16_f32 %0, %1, %2" : "=v"(r) : "v"(a), "v"(b));
  return r;
}

// ---------------------------------------------------------------------------
// Shared MFMA tile helper: C[64 rows x 128 cols] = A(lds,bf16,swizzled) @ Wp.
// Wave w owns rows 16w..16w+15. A-read: row 16w+l15, chunk (4ks+g)^(row&7).
// Wp packed: elem((nb*4+ks)*4+g)*16+l15)*8+i = W[32ks+8g+i][16nb+l15].
// D: lane(g,l15) holds rows 16w+4g+r, cols 16nb+l15.  (layouts verified by
// the attention kernel which uses identical mappings.)
// ---------------------------------------------------------------------------
__device__ inline void frag_gemm(const ushort* lds, const ushort* wp,
                                 int w, int g, int l15, f32x4 acc[8]) {
  #pragma unroll
  for (int nb = 0; nb < 8; nb++) acc[nb] = (f32x4){0.f, 0.f, 0.f, 0.f};
  #pragma unroll
  for (int ks = 0; ks < 4; ks++) {
    const char* asrc = (const char*)lds + (16 * w + l15) * 256 +
                       (((4 * ks + g) ^ (l15 & 7)) << 4);
    short8 af = *(const short8*)asrc;
    const ushort* wb = wp + (size_t)(ks * 4 + g) * 128 + l15 * 8;
    #pragma unroll
    for (int nb = 0; nb < 8; nb++) {
      short8 bf = *(const short8*)(wb + (size_t)nb * 2048);
      acc[nb] = __builtin_amdgcn_mfma_f32_16x16x32_bf16(af, bf, acc[nb], 0, 0, 0);
    }
  }
}

// LN stats over the 128 cols of each of the lane's 4 rows (16-lane shfl).
__device__ inline void row_ln_stats(const f32x4 acc[8], float mean[4],
                                    float rstd[4]) {
  f32x4 sum = acc[0], sq = acc[0] * acc[0];
  #pragma unroll
  for (int nb = 1; nb < 8; nb++) { sum += acc[nb]; sq += acc[nb] * acc[nb]; }
  #pragma unroll
  for (int o = 1; o <= 8; o <<= 1) {
    #pragma unroll
    for (int r = 0; r < 4; r++) {
      sum[r] += __shfl_xor(sum[r], o);
      sq[r]  += __shfl_xor(sq[r], o);
    }
  }
  #pragma unroll
  for (int r = 0; r < 4; r++) {
    mean[r] = sum[r] * (1.0f / 128.0f);
    float var = sq[r] * (1.0f / 128.0f) - mean[r] * mean[r];
    rstd[r] = rsqrtf(var + 1e-5f);
  }
}

// ---------------------------------------------------------------------------
// Kernel 0: pack 15 fp32 [128][128] weights into bf16 fragment order.
// Wq (type 1) folded with log2e/sqrt(C) scale.
// ---------------------------------------------------------------------------
__global__ __launch_bounds__(256) void k_prep(
    const float* __restrict__ mlpW, const float* __restrict__ Wq,
    const float* __restrict__ Wk, const float* __restrict__ Wv,
    const float* __restrict__ Wo, ushort* __restrict__ Wp) {
  const int b = blockIdx.x;          // 0..119
  const int m = b >> 3, nb = b & 7;  // matrix id = layer*5+type
  const int layer = m / 5, type = m % 5;
  const float* src;
  switch (type) {
    case 0:  src = mlpW + layer * CH * CH; break;
    case 1:  src = Wq + layer * CH * CH; break;
    case 2:  src = Wk + layer * CH * CH; break;
    case 3:  src = Wv + layer * CH * CH; break;
    default: src = Wo + layer * CH * CH; break;
  }
  const float mul = (type == 1) ? 0.12751879524143007f : 1.0f;
  const int tid = threadIdx.x;
  const int ks = tid >> 6, g = (tid >> 4) & 3, l15 = tid & 15;
  short8 v;
  #pragma unroll
  for (int i = 0; i < 8; i++)
    v[i] = (short)f2bf(src[(32 * ks + 8 * g + i) * CH + 16 * nb + l15] * mul);
  *(short8*)(Wp + (size_t)m * 16384 +
             (size_t)(((nb * 4 + ks) * 4 + g) * 16 + l15) * 8) = v;
}

// ---------------------------------------------------------------------------
// Kernel 1: embedding  feat = [corr_feat, centered(kp)] @ W_in + b_in
// ---------------------------------------------------------------------------
__global__ __launch_bounds__(128) void k_embed(
    const float* __restrict__ refp, const float* __restrict__ srcp,
    const float* __restrict__ cf, const float* __restrict__ Win,
    const float* __restrict__ bin, float* __restrict__ out) {
  const int row = blockIdx.x, j = threadIdx.x;
  __shared__ float inb[12];
  __shared__ float mkp;
  if (j < 6)       inb[j] = cf[row * 6 + j];
  else if (j < 9)  inb[j] = refp[row * 3 + (j - 6)];
  else if (j < 12) inb[j] = srcp[row * 3 + (j - 9)];
  __syncthreads();
  if (j == 0) {
    float s = inb[6] + inb[7] + inb[8] + inb[9] + inb[10] + inb[11];
    mkp = s * (1.0f / 6.0f);
  }
  __syncthreads();
  float acc = bin[j];
  #pragma unroll
  for (int kk = 0; kk < 12; kk++) {
    float x = inb[kk] - (kk >= 6 ? mkp : 0.0f);
    acc = fmaf(x, Win[kk * CH + j], acc);
  }
  out[row * CH + j] = acc;
}

// ---------------------------------------------------------------------------
// Kernel 2: MFMA fused UnaryBlock + QKV.  96 blocks x 256 thr (4 waves),
// 64 rows/block.  mlp GEMM -> in-fragment LN -> leaky -> h tile (LDS bf16,
// swizzled) -> Q/K/V GEMMs.  V written transposed + chunk-permuted (same
// global layout as previous rounds; attn kernel unchanged).
// ---------------------------------------------------------------------------
__global__ __launch_bounds__(256) void k_mlp_qkv(
    const float* __restrict__ X, const ushort* __restrict__ Wp,
    const float* __restrict__ b, const float* __restrict__ g_,
    const float* __restrict__ beta,
    const float* __restrict__ bq, const float* __restrict__ bk,
    const float* __restrict__ bv,
    float* __restrict__ T, ushort* __restrict__ Q, ushort* __restrict__ K,
    ushort* __restrict__ Vt) {
  const int tid = threadIdx.x;
  const int w = tid >> 6, ln = tid & 63;
  const int l15 = ln & 15, g = ln >> 4;
  const int rowbase = blockIdx.x * 64;

  __shared__ ushort xsb[64 * 128];   // bf16 input tile, swizzled
  __shared__ ushort hs[64 * 128];    // bf16 h tile, swizzled (later: V bounce, plain)

  // ---- stage X (fp32 -> bf16, swizzled) ----
  #pragma unroll
  for (int s = 0; s < 4; s++) {
    int c = tid + 256 * s;
    int row = c >> 4, c8 = c & 15;
    const float* src = X + (size_t)(rowbase + row) * CH + c8 * 8;
    f32x4 a = *(const f32x4*)src;
    f32x4 b2 = *(const f32x4*)(src + 4);
    union { unsigned u[4]; short8 s8; } P;
    P.u[0] = cvtpk(a[0], a[1]);  P.u[1] = cvtpk(a[2], a[3]);
    P.u[2] = cvtpk(b2[0], b2[1]); P.u[3] = cvtpk(b2[2], b2[3]);
    *(short8*)((char*)xsb + row * 256 + ((c8 ^ (row & 7)) << 4)) = P.s8;
  }
  __syncthreads();

  // ---- mlp GEMM + bias + LN + leaky ----
  f32x4 acc[8];
  frag_gemm(xsb, Wp, w, g, l15, acc);
  #pragma unroll
  for (int nb = 0; nb < 8; nb++) {
    float bb = b[16 * nb + l15];
    #pragma unroll
    for (int r = 0; r < 4; r++) acc[nb][r] += bb;
  }
  float mean[4], rstd[4];
  row_ln_stats(acc, mean, rstd);
  #pragma unroll
  for (int nb = 0; nb < 8; nb++) {
    float gam = g_[16 * nb + l15], bet = beta[16 * nb + l15];
    #pragma unroll
    for (int r = 0; r < 4; r++) {
      float y = (acc[nb][r] - mean[r]) * rstd[r] * gam + bet;
      y = (y > 0.0f) ? y : 0.1f * y;
      int lrow = 16 * w + 4 * g + r;
      T[(size_t)(rowbase + lrow) * CH + 16 * nb + l15] = y;
      int chunk = 2 * nb + (l15 >> 3);
      *(ushort*)((char*)hs + lrow * 256 + ((chunk ^ (lrow & 7)) << 4) +
                 (l15 & 7) * 2) = f2bf(y);
    }
  }
  __syncthreads();

  // ---- Q ----
  frag_gemm(hs, Wp + 16384, w, g, l15, acc);
  const float scale = 0.12751879524143007f;
  #pragma unroll
  for (int nb = 0; nb < 8; nb++) {
    float bb = bq[16 * nb + l15] * scale;
    #pragma unroll
    for (int r = 0; r < 4; r++)
      Q[(size_t)(rowbase + 16 * w + 4 * g + r) * CH + 16 * nb + l15] =
          f2bf(acc[nb][r] + bb);
  }
  // ---- K ----
  frag_gemm(hs, Wp + 2 * 16384, w, g, l15, acc);
  #pragma unroll
  for (int nb = 0; nb < 8; nb++) {
    float bb = bk[16 * nb + l15];
    #pragma unroll
    for (int r = 0; r < 4; r++)
      K[(size_t)(rowbase + 16 * w + 4 * g + r) * CH + 16 * nb + l15] =
          f2bf(acc[nb][r] + bb);
  }
  // ---- V (bounce through LDS for coalesced transposed store) ----
  frag_gemm(hs, Wp + 3 * 16384, w, g, l15, acc);
  float vb_[8];
  #pragma unroll
  for (int nb = 0; nb < 8; nb++) vb_[nb] = bv[16 * nb + l15];
  __syncthreads();   // all hs A-frag reads done; hs reusable (plain layout)
  #pragma unroll
  for (int nb = 0; nb < 8; nb++)
    #pragma unroll
    for (int r = 0; r < 4; r++)
      hs[(16 * w + 4 * g + r) * 128 + 16 * nb + l15] = f2bf(acc[nb][r] + vb_[nb]);
  __syncthreads();
  #pragma unroll
  for (int s = 0; s < 8; s++) {
    int item = tid + 256 * s;         // 2048: ch(128) x grp(16)
    int ch = item >> 4, grp = item & 15;
    int k0 = grp * 4;
    int pos = 32 * ((k0 >> 5) & 1) + 8 * ((k0 >> 2) & 3) + 4 * ((k0 >> 4) & 1);
    ushort4 vv;
    vv.x = hs[(k0 + 0) * 128 + ch];
    vv.y = hs[(k0 + 1) * 128 + ch];
    vv.z = hs[(k0 + 2) * 128 + ch];
    vv.w = hs[(k0 + 3) * 128 + ch];
    *(ushort4*)(Vt + (size_t)ch * NPTS + rowbase + pos) = vv;
  }
}

// ---------------------------------------------------------------------------
// Kernel 3: MFMA flash attention, KV-split (unchanged from round 9).
// ---------------------------------------------------------------------------
__global__ __launch_bounds__(512, 4) void k_attn_mfma(
    const ushort* __restrict__ Q, const ushort* __restrict__ K,
    const ushort* __restrict__ Vt,
    const float* __restrict__ refp, const float* __restrict__ srcp,
    float* __restrict__ Opart, float* __restrict__ ML, int ntiles) {
  const int tid = threadIdx.x;
  const int w = tid >> 6, ln = tid & 63;
  const int l15 = ln & 15, g = ln >> 4;
  const int row0 = blockIdx.x * 128;
  const int seg = blockIdx.y;
  const int t0 = seg * ntiles;

  __shared__ ushort Ks[2][64][128];
  __shared__ ushort Vs[128][64];
  __shared__ float cs2[6][64];

  const int krow = tid >> 4;
  const int kc   = tid & 15;
  const int kofs = krow * 256 + (((kc ^ (krow & 7)) << 4));
  const int vch  = tid >> 3;
  const int vc   = tid & 7;
  const int vofs = vch * 128 + (((vc ^ (vch & 7)) << 4));

  short8 kreg0, kreg1, vreg0, vreg1;
  float cr[6];

  auto issue = [&](int t) {
    const ushort* kp = K + (size_t)(t * 64 + krow) * CH + kc * 8;
    kreg0 = *(const short8*)kp;
    kreg1 = *(const short8*)(kp + (size_t)32 * CH);
    const ushort* vp = Vt + (size_t)vch * NPTS + t * 64 + vc * 8;
    vreg0 = *(const short8*)vp;
    vreg1 = *(const short8*)(vp + (size_t)64 * NPTS);
    if (tid < 64) {
      int gj = t * 64 + tid;
      cr[0] = refp[gj * 3]; cr[1] = refp[gj * 3 + 1]; cr[2] = refp[gj * 3 + 2];
      cr[3] = srcp[gj * 3]; cr[4] = srcp[gj * 3 + 1]; cr[5] = srcp[gj * 3 + 2];
    }
  };

  short8 qf[4];
  {
    const ushort* qp = Q + (size_t)(row0 + 16 * w + l15) * CH + 8 * g;
    #pragma unroll
    for (int ks = 0; ks < 4; ks++) qf[ks] = *(const short8*)(qp + 32 * ks);
  }
  const int qrow = row0 + 16 * w + l15;
  const float rq0 = refp[qrow * 3], rq1 = refp[qrow * 3 + 1], rq2 = refp[qrow * 3 + 2];
  const float sq0 = srcp[qrow * 3], sq1 = srcp[qrow * 3 + 1], sq2 = srcp[qrow * 3 + 2];

  f32x4 oacc[8];
  #pragma unroll
  for (int n = 0; n < 8; n++) oacc[n] = (f32x4){0.f, 0.f, 0.f, 0.f};
  float m = -1e30f, l = 0.0f;
  const float invs2 = 1.0f / (0.3f * 0.3f);

  issue(t0);
  *(short8*)((char*)&Ks[0][0][0] + kofs) = kreg0;
  *(short8*)((char*)&Ks[0][0][0] + kofs + 32 * 256) = kreg1;
  *(short8*)((char*)&Vs[0][0] + vofs) = vreg0;
  *(short8*)((char*)&Vs[0][0] + vofs + 64 * 128) = vreg1;
  if (tid < 64) {
    #pragma unroll
    for (int d = 0; d < 6; d++) cs2[d][tid] = cr[d];
  }
  __syncthreads();

  int cb = 0;
  for (int tt = 0; tt < ntiles; tt++) {
    if (tt + 1 < ntiles) issue(t0 + tt + 1);

    f32x4 acc[4];
    #pragma unroll
    for (int nb = 0; nb < 4; nb++) acc[nb] = (f32x4){0.f, 0.f, 0.f, 0.f};
    __builtin_amdgcn_s_setprio(1);
    #pragma unroll
    for (int ks = 0; ks < 4; ks++) {
      #pragma unroll
      for (int nb = 0; nb < 4; nb++) {
        const char* src = (const char*)&Ks[cb][0][0] + (16 * nb + l15) * 256 +
                          (((4 * ks + g) ^ (l15 & 7)) << 4);
        short8 af = *(const short8*)src;
        acc[nb] = __builtin_amdgcn_mfma_f32_16x16x32_bf16(af, qf[ks], acc[nb], 0, 0, 0);
      }
    }
    __builtin_amdgcn_s_setprio(0);

    float plog[4][4];
    #pragma unroll
    for (int nb = 0; nb < 4; nb++) {
      const int kb = 16 * nb + 4 * g;
      #pragma unroll
      for (int pp = 0; pp < 2; pp++) {
        const int k2 = kb + 2 * pp;
        f32x2 cx = *(const f32x2*)&cs2[0][k2];
        f32x2 cy = *(const f32x2*)&cs2[1][k2];
        f32x2 cz = *(const f32x2*)&cs2[2][k2];
        f32x2 dx = splat2(rq0) - cx, dy = splat2(rq1) - cy, dz = splat2(rq2) - cz;
        f32x2 d2r = dx * dx + dy * dy + dz * dz;
        cx = *(const f32x2*)&cs2[3][k2];
        cy = *(const f32x2*)&cs2[4][k2];
        cz = *(const f32x2*)&cs2[5][k2];
        dx = splat2(sq0) - cx; dy = splat2(sq1) - cy; dz = splat2(sq2) - cz;
        f32x2 d2s = dx * dx + dy * dy + dz * dz;
        f32x2 prod = d2r * d2s;
        f32x2 sum2 = d2r + d2s;
        float s0 = fsqrt(prod[0]), s1 = fsqrt(prod[1]);
        float dd20 = fmaf(-2.0f, s0, sum2[0]);
        float dd21 = fmaf(-2.0f, s1, sum2[1]);
        float gg0 = fmaxf(fmaf(dd20, -invs2, 1.0f), 0.0f);
        float gg1 = fmaxf(fmaf(dd21, -invs2, 1.0f), 0.0f);
        plog[nb][2 * pp]     = gg0 * acc[nb][2 * pp];
        plog[nb][2 * pp + 1] = gg1 * acc[nb][2 * pp + 1];
      }
    }

    float tm = fmaxf(fmaxf(plog[0][0], plog[0][1]), fmaxf(plog[0][2], plog[0][3]));
    #pragma unroll
    for (int nb = 1; nb < 4; nb++) {
      float t2 = fmaxf(fmaxf(plog[nb][0], plog[nb][1]),
                       fmaxf(plog[nb][2], plog[nb][3]));
      tm = fmaxf(tm, t2);
    }
    tm = fmaxf(tm, __shfl_xor(tm, 16));
    tm = fmaxf(tm, __shfl_xor(tm, 32));
    if (__any(tm > m + 11.0f)) {
      float nm = fmaxf(m, tm);
      float rsc = fexp2(m - nm);
      l *= rsc;
      #pragma unroll
      for (int n = 0; n < 8; n++) oacc[n] *= rsc;
      m = nm;
    }
    float psum = 0.0f;
    #pragma unroll
    for (int nb = 0; nb < 4; nb++)
      #pragma unroll
      for (int r = 0; r < 4; r++) {
        float p = fexp2(plog[nb][r] - m);
        plog[nb][r] = p;
        psum += p;
      }
    psum += __shfl_xor(psum, 16);
    psum += __shfl_xor(psum, 32);
    l += psum;

    unsigned pk[4][2];
    #pragma unroll
    for (int nb = 0; nb < 4; nb++) {
      pk[nb][0] = cvtpk(plog[nb][0], plog[nb][1]);
      pk[nb][1] = cvtpk(plog[nb][2], plog[nb][3]);
    }

    __syncthreads();   // barrier B

    if (tt + 1 < ntiles) {
      *(short8*)((char*)&Ks[cb ^ 1][0][0] + kofs) = kreg0;
      *(short8*)((char*)&Ks[cb ^ 1][0][0] + kofs + 32 * 256) = kreg1;
      if (tid < 64) {
        #pragma unroll
        for (int d = 0; d < 6; d++) cs2[d][tid] = cr[d];
      }
    }

    union U16 { i32x4 i; short8 s; };
    __builtin_amdgcn_s_setprio(1);
    #pragma unroll
    for (int ks2 = 0; ks2 < 2; ks2++) {
      U16 bfr;
      bfr.i[0] = (int)pk[2 * ks2][0];
      bfr.i[1] = (int)pk[2 * ks2][1];
      bfr.i[2] = (int)pk[2 * ks2 + 1][0];
      bfr.i[3] = (int)pk[2 * ks2 + 1][1];
      #pragma unroll
      for (int nb2 = 0; nb2 < 8; nb2++) {
        const char* vsrc = (const char*)&Vs[0][0] + (16 * nb2 + l15) * 128 +
                           (((4 * ks2 + g) ^ (l15 & 7)) << 4);
        short8 vf = *(const short8*)vsrc;
        oacc[nb2] = __builtin_amdgcn_mfma_f32_16x16x32_bf16(vf, bfr.s, oacc[nb2], 0, 0, 0);
      }
    }
    __builtin_amdgcn_s_setprio(0);

    __syncthreads();   // barrier C

    if (tt + 1 < ntiles) {
      *(short8*)((char*)&Vs[0][0] + vofs) = vreg0;
      *(short8*)((char*)&Vs[0][0] + vofs + 64 * 128) = vreg1;
    }
    cb ^= 1;
  }

  {
    float* op = Opart + ((size_t)seg * NPTS + qrow) * CH;
    #pragma unroll
    for (int nb2 = 0; nb2 < 8; nb2++)
      *(f32x4*)(op + 16 * nb2 + 4 * g) = oacc[nb2];
    if (g == 0) {
      ML[((size_t)seg * NPTS + qrow) * 2]     = m;
      ML[((size_t)seg * NPTS + qrow) * 2 + 1] = l;
    }
  }
}

// ---------------------------------------------------------------------------
// Kernel 4: MFMA fused combine + out-proj + residual + LN.
// 96 blocks x 256 thr, 64 rows/block.
// ---------------------------------------------------------------------------
__global__ __launch_bounds__(256) void k_out(
    const float* __restrict__ Opart, const float* __restrict__ ML, int NS,
    const ushort* __restrict__ WpO, const float* __restrict__ bo,
    const float* __restrict__ g_, const float* __restrict__ beta,
    const float* __restrict__ res, float* __restrict__ Fout) {
  const int tid = threadIdx.x;
  const int w = tid >> 6, ln = tid & 63;
  const int l15 = ln & 15, g = ln >> 4;
  const int rowbase = blockIdx.x * 64;

  __shared__ ushort hs[64 * 128];
  __shared__ float wscL[17][64];

  if (tid < 64) {
    int row = rowbase + tid;
    float M = -1e30f;
    for (int s = 0; s < NS; s++)
      M = fmaxf(M, ML[((size_t)s * NPTS + row) * 2]);
    float L = 0.0f;
    for (int s = 0; s < NS; s++) {
      float ms = ML[((size_t)s * NPTS + row) * 2];
      float ls = ML[((size_t)s * NPTS + row) * 2 + 1];
      float wsc = fexp2(ms - M);
      wscL[s][tid] = wsc;
      L += wsc * ls;
    }
    wscL[16][tid] = 1.0f / L;
  }
  __syncthreads();

  // ---- combine -> bf16 h tile (swizzled) ----
  #pragma unroll
  for (int s4 = 0; s4 < 4; s4++) {
    int c = tid + 256 * s4;
    int row = c >> 4, c8 = c & 15;
    f32x4 a = (f32x4){0.f, 0.f, 0.f, 0.f};
    f32x4 b2 = (f32x4){0.f, 0.f, 0.f, 0.f};
    for (int s = 0; s < NS; s++) {
      float wsc = wscL[s][row];
      const float* op = Opart + ((size_t)s * NPTS + rowbase + row) * CH + c8 * 8;
      f32x4 o1 = *(const f32x4*)op;
      f32x4 o2 = *(const f32x4*)(op + 4);
      #pragma unroll
      for (int q = 0; q < 4; q++) {
        a[q] = fmaf(wsc, o1[q], a[q]);
        b2[q] = fmaf(wsc, o2[q], b2[q]);
      }
    }
    float invL = wscL[16][row];
    union { unsigned u[4]; short8 s8; } P;
    P.u[0] = cvtpk(a[0] * invL, a[1] * invL);
    P.u[1] = cvtpk(a[2] * invL, a[3] * invL);
    P.u[2] = cvtpk(b2[0] * invL, b2[1] * invL);
    P.u[3] = cvtpk(b2[2] * invL, b2[3] * invL);
    *(short8*)((char*)hs + row * 256 + ((c8 ^ (row & 7)) << 4)) = P.s8;
  }
  __syncthreads();

  // ---- Wo GEMM + bias + residual + LN ----
  f32x4 acc[8];
  frag_gemm(hs, WpO, w, g, l15, acc);
  #pragma unroll
  for (int nb = 0; nb < 8; nb++) {
    float bb = bo[16 * nb + l15];
    #pragma unroll
    for (int r = 0; r < 4; r++)
      acc[nb][r] += bb + res[(size_t)(rowbase + 16 * w + 4 * g + r) * CH +
                             16 * nb + l15];
  }
  float mean[4], rstd[4];
  row_ln_stats(acc, mean, rstd);
  #pragma unroll
  for (int nb = 0; nb < 8; nb++) {
    float gam = g_[16 * nb + l15], bet = beta[16 * nb + l15];
    #pragma unroll
    for (int r = 0; r < 4; r++)
      Fout[(size_t)(rowbase + 16 * w + 4 * g + r) * CH + 16 * nb + l15] =
          (acc[nb][r] - mean[r]) * rstd[r] * gam + bet;
  }
}

// ---------------------------------------------------------------------------
// Kernel 5: final row normalize + classifier MLP + sigmoid
// ---------------------------------------------------------------------------
__global__ __launch_bounds__(128) void k_final(
    const float* __restrict__ F,
    const float* __restrict__ c1W, const float* __restrict__ c1b,
    const float* __restrict__ c2W, const float* __restrict__ c2b,
    const float* __restrict__ c3W, const float* __restrict__ c3b,
    float* __restrict__ out) {
  const int row = blockIdx.x, j = threadIdx.x;
  __shared__ float xs[CH];
  __shared__ float h1[32];
  __shared__ float h2[32];
  __shared__ float red[2];
  float x = F[row * CH + j];
  float ss = x * x;
  #pragma unroll
  for (int o = 32; o; o >>= 1) ss += __shfl_xor(ss, o);
  if ((j & 63) == 0) red[j >> 6] = ss;
  __syncthreads();
  float norm = sqrtf(red[0] + red[1]);
  float xn = x / fmaxf(norm, 1e-12f);
  xs[j] = xn;
  out[row * CH + j] = xn;
  __syncthreads();
  if (j < 32) {
    float a = c1b[j];
    for (int kk = 0; kk < CH; kk++) a = fmaf(xs[kk], c1W[kk * 32 + j], a);
    h1[j] = fmaxf(a, 0.0f);
  }
  __syncthreads();
  if (j < 32) {
    float a = c2b[j];
    #pragma unroll
    for (int kk = 0; kk < 32; kk++) a = fmaf(h1[kk], c2W[kk * 32 + j], a);
    h2[j] = fmaxf(a, 0.0f);
  }
  __syncthreads();
  if (j == 0) {
    float a = c3b[0];
    #pragma unroll
    for (int kk = 0; kk < 32; kk++) a = fmaf(h2[kk], c3W[kk], a);
    out[NPTS * CH + row] = 1.0f / (1.0f + __expf(-a));
  }
}

// ---------------------------------------------------------------------------
extern "C" void kernel_launch(void* const* d_in, const int* in_sizes, int n_in,
                              void* d_out, int out_size, void* d_ws, size_t ws_size,
                              hipStream_t stream) {
  const float* refp = (const float*)d_in[0];
  const float* srcp = (const float*)d_in[1];
  const float* cf   = (const float*)d_in[2];
  const float* Win  = (const float*)d_in[3];
  const float* bin  = (const float*)d_in[4];
  const float* mlpW = (const float*)d_in[5];
  const float* mlpb = (const float*)d_in[6];
  const float* mlpg = (const float*)d_in[7];
  const float* mlpbeta = (const float*)d_in[8];
  const float* Wq = (const float*)d_in[9];
  const float* bq = (const float*)d_in[10];
  const float* Wk = (const float*)d_in[11];
  const float* bk = (const float*)d_in[12];
  const float* Wv = (const float*)d_in[13];
  const float* bv = (const float*)d_in[14];
  const float* Wo = (const float*)d_in[15];
  const float* bo = (const float*)d_in[16];
  const float* lng = (const float*)d_in[17];
  const float* lnb = (const float*)d_in[18];
  const float* c1W = (const float*)d_in[19];
  const float* c1b = (const float*)d_in[20];
  const float* c2W = (const float*)d_in[21];
  const float* c2b = (const float*)d_in[22];
  const float* c3W = (const float*)d_in[23];
  const float* c3b = (const float*)d_in[24];
  float* out = (float*)d_out;

  const size_t NC = (size_t)NPTS * CH;
  float* F = (float*)d_ws;
  float* T = F + NC;
  ushort* Qb  = (ushort*)(T + NC);
  ushort* Kb  = Qb + NC;
  ushort* Vtb = Kb + NC;
  ushort* Wpb = Vtb + NC;                       // 15 * 16384 bf16
  float* Opart = (float*)(Wpb + 15 * 16384);

  const size_t base_bytes = 2 * NC * 4 + 3 * NC * 2 + (size_t)15 * 16384 * 2;
  int NS = 1;
  for (int cand = 16; cand >= 2; cand >>= 1) {
    size_t need = base_bytes + (size_t)cand * (NC * 4 + NPTS * 8);
    if (need <= ws_size) { NS = cand; break; }
  }
  float* ML = Opart + (size_t)NS * NC;
  const int ntiles = NPTS / 64 / NS;

  k_prep<<<120, 256, 0, stream>>>(mlpW, Wq, Wk, Wv, Wo, Wpb);
  k_embed<<<NPTS, 128, 0, stream>>>(refp, srcp, cf, Win, bin, F);
  for (int i = 0; i < 3; i++) {
    const int o1 = i * CH;
    const ushort* WpL = Wpb + (size_t)i * 5 * 16384;
    k_mlp_qkv<<<NPTS / 64, 256, 0, stream>>>(
        F, WpL, mlpb + o1, mlpg + o1, mlpbeta + o1,
        bq + o1, bk + o1, bv + o1, T, Qb, Kb, Vtb);
    dim3 agrid(NPTS / 128, NS);
    k_attn_mfma<<<agrid, 512, 0, stream>>>(Qb, Kb, Vtb, refp, srcp, Opart, ML, ntiles);
    k_out<<<NPTS / 64, 256, 0, stream>>>(Opart, ML, NS, WpL + 4 * 16384,
                                         bo + o1, lng + o1, lnb + o1, T, F);
  }
  k_final<<<NPTS, 128, 0, stream>>>(F, c1W, c1b, c2W, c2b, c3W, c3b, out);
}